// Round 1
// baseline (50.050 us; speedup 1.0000x reference)
//
#include <hip/hip_runtime.h>

// DMLoss: B=1024, Np=Ng=128, T=10 interpolation steps.
// Kernel 1: one block per batch; computes three partial sums (double) per batch.
// Kernel 2: reduces 1024 partials -> final scalar.

constexpr int NP = 128;
constexpr int NG = 128;
constexpr int TT = 10;
constexpr int NI = NG * TT;  // 1280 interpolated gt points

__global__ __launch_bounds__(256) void dm_main(
    const float* __restrict__ ini,   // [B, NP, 2] ini_pred_poly
    const float* __restrict__ pp,    // [B, NP, 2] pred_polys_
    const float* __restrict__ gt,    // [B, NG, 2] gt_polys
    const float* __restrict__ mask,  // [B, NG]
    double* __restrict__ partial)    // [B, 3] {pred2gt_sum, masked_sum, mask_sum}
{
    const int b   = blockIdx.x;
    const int tid = threadIdx.x;

    __shared__ float s_gt [NG * 2];
    __shared__ float s_ini[NP * 2];
    __shared__ float s_pp [NP * 2];
    __shared__ float s_it [NI * 2];   // interpolated gt points (10 KB)
    __shared__ float s_bd [256];
    __shared__ int   s_bi [256];
    __shared__ double s_red[12];      // 4 waves x 3 sums

    const float* gtb  = gt  + (size_t)b * NG * 2;
    const float* inib = ini + (size_t)b * NP * 2;
    const float* ppb  = pp  + (size_t)b * NP * 2;

    // Stage inputs (NG*2 == NP*2 == 256 == blockDim.x)
    s_gt [tid] = gtb [tid];
    s_ini[tid] = inib[tid];
    s_pp [tid] = ppb [tid];
    __syncthreads();

    // Interpolation: interp[n*T + t] = gt[n]*step + gt[n-1]*(1-step), step = t/T
    for (int i = tid; i < NI; i += 256) {
        const int n = i / TT;
        const int t = i - n * TT;
        const float step = (float)t / (float)TT;
        const float om   = 1.0f - step;
        const int   nprev = (n + NG - 1) & (NG - 1);
        const float cx = s_gt[2 * n],     cy = s_gt[2 * n + 1];
        const float px = s_gt[2 * nprev], py = s_gt[2 * nprev + 1];
        s_it[2 * i]     = cx * step + px * om;
        s_it[2 * i + 1] = cy * step + py * om;
    }
    __syncthreads();

    // ---- Part 1: for each pred point, nearest interp point (argmin over 1280) ----
    // Two threads per pred point; each scans one half (ascending -> first-occurrence).
    const int p    = tid & (NP - 1);
    const int half = tid >> 7;
    const float qx = s_ini[2 * p], qy = s_ini[2 * p + 1];
    float best = 3.4e38f;
    int   bi   = 0;
    const int i0 = half * (NI / 2);
    const int i1 = i0 + (NI / 2);
    #pragma unroll 4
    for (int i = i0; i < i1; ++i) {
        const float dx = s_it[2 * i]     - qx;   // broadcast LDS reads across the wave
        const float dy = s_it[2 * i + 1] - qy;
        const float d  = dx * dx + dy * dy;
        if (d < best) { best = d; bi = i; }
    }
    s_bd[tid] = best;
    s_bi[tid] = bi;
    __syncthreads();

    double l_p2g = 0.0, l_masked = 0.0, l_msum = 0.0;
    if (tid < NP) {
        // Combine halves; tie -> lower index (jnp.argmin first occurrence)
        const float dlo = s_bd[tid], dhi = s_bd[tid + 128];
        const int   ilo = s_bi[tid], ihi = s_bi[tid + 128];
        const int   idx = (dhi < dlo) ? ihi : ilo;
        const float nx = s_it[2 * idx], ny = s_it[2 * idx + 1];
        l_p2g = (double)fabsf(s_pp[2 * tid] - nx) + (double)fabsf(s_pp[2 * tid + 1] - ny);

        // ---- Part 2: for each gt vertex (g = tid), nearest pred point ----
        const float gx = s_gt[2 * tid], gy = s_gt[2 * tid + 1];
        float bd = 3.4e38f;
        int   bj = 0;
        #pragma unroll 4
        for (int j = 0; j < NP; ++j) {
            const float dx = gx - s_ini[2 * j];
            const float dy = gy - s_ini[2 * j + 1];
            const float d  = dx * dx + dy * dy;
            if (d < bd) { bd = d; bj = j; }
        }
        const float npx = s_pp[2 * bj], npy = s_pp[2 * bj + 1];
        const float m   = mask[(size_t)b * NG + tid];
        l_masked = (double)m * ((double)fabsf(npx - gx) + (double)fabsf(npy - gy));
        l_msum   = 2.0 * (double)m;
    }

    // Wave (64-lane) reduction, then cross-wave via LDS
    for (int off = 32; off > 0; off >>= 1) {
        l_p2g    += __shfl_down(l_p2g, off);
        l_masked += __shfl_down(l_masked, off);
        l_msum   += __shfl_down(l_msum, off);
    }
    const int wid = tid >> 6, lane = tid & 63;
    if (lane == 0) {
        s_red[wid * 3 + 0] = l_p2g;
        s_red[wid * 3 + 1] = l_masked;
        s_red[wid * 3 + 2] = l_msum;
    }
    __syncthreads();
    if (tid == 0) {
        partial[(size_t)b * 3 + 0] = s_red[0] + s_red[3] + s_red[6] + s_red[9];
        partial[(size_t)b * 3 + 1] = s_red[1] + s_red[4] + s_red[7] + s_red[10];
        partial[(size_t)b * 3 + 2] = s_red[2] + s_red[5] + s_red[8] + s_red[11];
    }
}

__global__ __launch_bounds__(256) void dm_final(
    const double* __restrict__ partial, int nb, double inv_count, float* __restrict__ out)
{
    const int tid = threadIdx.x;
    double a = 0.0, c = 0.0, d = 0.0;
    for (int b = tid; b < nb; b += 256) {
        a += partial[(size_t)b * 3 + 0];
        c += partial[(size_t)b * 3 + 1];
        d += partial[(size_t)b * 3 + 2];
    }
    for (int off = 32; off > 0; off >>= 1) {
        a += __shfl_down(a, off);
        c += __shfl_down(c, off);
        d += __shfl_down(d, off);
    }
    __shared__ double s[12];
    const int wid = tid >> 6, lane = tid & 63;
    if (lane == 0) { s[wid * 3] = a; s[wid * 3 + 1] = c; s[wid * 3 + 2] = d; }
    __syncthreads();
    if (tid == 0) {
        const double at = s[0] + s[3] + s[6] + s[9];
        const double ct = s[1] + s[4] + s[7] + s[10];
        const double dt = s[2] + s[5] + s[8] + s[11];
        const double loss = ct / (dt + 1.0) + at * inv_count;  // masked/(masksum+1) + mean(p2g)
        out[0] = (float)(loss * 0.5);
    }
}

extern "C" void kernel_launch(void* const* d_in, const int* in_sizes, int n_in,
                              void* d_out, int out_size, void* d_ws, size_t ws_size,
                              hipStream_t stream) {
    const float* ini  = (const float*)d_in[0];  // ini_pred_poly [B,128,2]
    const float* pp   = (const float*)d_in[1];  // pred_polys_   [B,128,2]
    const float* gt   = (const float*)d_in[2];  // gt_polys      [B,128,2]
    const float* mask = (const float*)d_in[3];  // keyPointsMask [B,128]
    float* out = (float*)d_out;

    const int B = in_sizes[0] / (NP * 2);
    double* partial = (double*)d_ws;            // B*3 doubles (24 KB)

    dm_main<<<B, 256, 0, stream>>>(ini, pp, gt, mask, partial);
    const double inv_count = 1.0 / ((double)B * NP * 2);
    dm_final<<<1, 256, 0, stream>>>(partial, B, inv_count, out);
}

// Round 2
// 24.135 us; speedup vs baseline: 2.0738x; 2.0738x over previous
//
#include <hip/hip_runtime.h>

// DMLoss: B=1024, Np=Ng=128, T=10.
// Round 2: replace the 1280-point brute-force argmin (LDS-pipe bound,
// 2x ds_read_b32 per point) with per-segment closed-form quadratic minimization:
// for segment n (prev=gt[n-1] -> cur=gt[n]), d(t) is convex quadratic in t;
// t* = clamp(round(10*dot(w,e)/|e|^2), 0, 9). 10x fewer evals, ~20x fewer LDS ops.

constexpr int NP = 128;
constexpr int NG = 128;
constexpr int TT = 10;

__global__ __launch_bounds__(256) void dm_main(
    const float* __restrict__ ini,   // [B, NP, 2] ini_pred_poly
    const float* __restrict__ pp,    // [B, NP, 2] pred_polys_
    const float* __restrict__ gt,    // [B, NG, 2] gt_polys
    const float* __restrict__ mask,  // [B, NG]
    double* __restrict__ partial)    // [B, 3] {pred2gt_sum, masked_sum, mask_sum}
{
    const int b   = blockIdx.x;
    const int tid = threadIdx.x;

    __shared__ float2 s_gt [NG];
    __shared__ float2 s_ini[NP];
    __shared__ float2 s_pp [NP];
    __shared__ float  s_bd [256];
    __shared__ int    s_bi [256];
    __shared__ double s_red[12];

    // Stage inputs (256 floats each, one per thread)
    ((float*)s_gt )[tid] = gt [(size_t)b * NG * 2 + tid];
    ((float*)s_ini)[tid] = ini[(size_t)b * NP * 2 + tid];
    ((float*)s_pp )[tid] = pp [(size_t)b * NP * 2 + tid];
    __syncthreads();

    const int p    = tid & (NP - 1);
    const int half = tid >> 7;            // wave-uniform (waves 0-1: 0, waves 2-3: 1)
    const float2 q = s_ini[p];

    // ---- Part 1: nearest interp point via per-segment quadratic ----
    // Thread scans 64 segments; 2 threads per pred point (halves of the polygon).
    const int s0 = half * (NG / 2);
    float2 prev = s_gt[(s0 + NG - 1) & (NG - 1)];
    float best = 3.4e38f;
    int   bi   = 0;
    int   base = s0 * TT;
    #pragma unroll 4
    for (int k = 0; k < NG / 2; ++k) {
        const float2 cur = s_gt[s0 + k];           // broadcast ds_read_b64
        const float ex = cur.x - prev.x, ey = cur.y - prev.y;
        const float wx = q.x  - prev.x,  wy = q.y  - prev.y;
        const float ee = fmaxf(ex * ex + ey * ey, 1e-30f);
        const float tf = (wx * ex + wy * ey) * __builtin_amdgcn_rcpf(ee) * 10.0f;
        float tc = rintf(tf);
        tc = fminf(fmaxf(tc, 0.0f), 9.0f);
        const float sd  = tc * 0.1f;               // model distance only
        const float dqx = wx - sd * ex;
        const float dqy = wy - sd * ey;
        const float d   = dqx * dqx + dqy * dqy;
        const int   gi  = base + (int)tc;
        if (d < best) { best = d; bi = gi; }
        base += TT;
        prev = cur;
    }
    s_bd[tid] = best;
    s_bi[tid] = bi;
    __syncthreads();

    double l_p2g = 0.0, l_masked = 0.0, l_msum = 0.0;
    if (tid < NP) {
        // Combine halves (tie -> lower index), then exact reference interp point
        const int idx = (s_bd[tid + 128] < s_bd[tid]) ? s_bi[tid + 128] : s_bi[tid];
        const int n = idx / TT;
        const int t = idx - n * TT;
        const float step = (float)t / 10.0f;       // exact ref: arange(T)/T (t*0.1f differs at t=9!)
        const float om   = 1.0f - step;
        const float2 c  = s_gt[n];
        const float2 pr = s_gt[(n + NG - 1) & (NG - 1)];
        const float nx = c.x * step + pr.x * om;
        const float ny = c.y * step + pr.y * om;
        const float2 mp = s_pp[tid];
        l_p2g = (double)fabsf(mp.x - nx) + (double)fabsf(mp.y - ny);
    }
    __syncthreads();   // s_bd/s_bi about to be reused

    // ---- Part 2: for each gt vertex, nearest pred point (2 threads/vertex) ----
    {
        const float2 gv = s_gt[p];
        float bd = 3.4e38f;
        int   bj = 0;
        const int j0 = half * (NP / 2);
        #pragma unroll 4
        for (int k = 0; k < NP / 2; ++k) {
            const float2 pv = s_ini[j0 + k];       // broadcast ds_read_b64
            const float dx = gv.x - pv.x, dy = gv.y - pv.y;
            const float d  = dx * dx + dy * dy;
            if (d < bd) { bd = d; bj = j0 + k; }
        }
        s_bd[tid] = bd;
        s_bi[tid] = bj;
    }
    __syncthreads();
    if (tid < NP) {
        const int bj = (s_bd[tid + 128] < s_bd[tid]) ? s_bi[tid + 128] : s_bi[tid];
        const float2 npt = s_pp[bj];
        const float2 gv  = s_gt[tid];
        const float  m   = mask[(size_t)b * NG + tid];
        l_masked = (double)m * ((double)fabsf(npt.x - gv.x) + (double)fabsf(npt.y - gv.y));
        l_msum   = 2.0 * (double)m;
    }

    // Wave reduction, then cross-wave via LDS
    for (int off = 32; off > 0; off >>= 1) {
        l_p2g    += __shfl_down(l_p2g, off);
        l_masked += __shfl_down(l_masked, off);
        l_msum   += __shfl_down(l_msum, off);
    }
    const int wid = tid >> 6, lane = tid & 63;
    if (lane == 0) {
        s_red[wid * 3 + 0] = l_p2g;
        s_red[wid * 3 + 1] = l_masked;
        s_red[wid * 3 + 2] = l_msum;
    }
    __syncthreads();
    if (tid == 0) {
        partial[(size_t)b * 3 + 0] = s_red[0] + s_red[3] + s_red[6] + s_red[9];
        partial[(size_t)b * 3 + 1] = s_red[1] + s_red[4] + s_red[7] + s_red[10];
        partial[(size_t)b * 3 + 2] = s_red[2] + s_red[5] + s_red[8] + s_red[11];
    }
}

__global__ __launch_bounds__(256) void dm_final(
    const double* __restrict__ partial, int nb, double inv_count, float* __restrict__ out)
{
    const int tid = threadIdx.x;
    double a = 0.0, c = 0.0, d = 0.0;
    for (int b = tid; b < nb; b += 256) {
        a += partial[(size_t)b * 3 + 0];
        c += partial[(size_t)b * 3 + 1];
        d += partial[(size_t)b * 3 + 2];
    }
    for (int off = 32; off > 0; off >>= 1) {
        a += __shfl_down(a, off);
        c += __shfl_down(c, off);
        d += __shfl_down(d, off);
    }
    __shared__ double s[12];
    const int wid = tid >> 6, lane = tid & 63;
    if (lane == 0) { s[wid * 3] = a; s[wid * 3 + 1] = c; s[wid * 3 + 2] = d; }
    __syncthreads();
    if (tid == 0) {
        const double at = s[0] + s[3] + s[6] + s[9];
        const double ct = s[1] + s[4] + s[7] + s[10];
        const double dt = s[2] + s[5] + s[8] + s[11];
        const double loss = ct / (dt + 1.0) + at * inv_count;
        out[0] = (float)(loss * 0.5);
    }
}

extern "C" void kernel_launch(void* const* d_in, const int* in_sizes, int n_in,
                              void* d_out, int out_size, void* d_ws, size_t ws_size,
                              hipStream_t stream) {
    const float* ini  = (const float*)d_in[0];
    const float* pp   = (const float*)d_in[1];
    const float* gt   = (const float*)d_in[2];
    const float* mask = (const float*)d_in[3];
    float* out = (float*)d_out;

    const int B = in_sizes[0] / (NP * 2);
    double* partial = (double*)d_ws;

    dm_main<<<B, 256, 0, stream>>>(ini, pp, gt, mask, partial);
    const double inv_count = 1.0 / ((double)B * NP * 2);
    dm_final<<<1, 256, 0, stream>>>(partial, B, inv_count, out);
}